// Round 8
// baseline (204.179 us; speedup 1.0000x reference)
//
#include <hip/hip_runtime.h>
#include <hip/hip_bf16.h>

#define B_ 4
#define S_ 1024
#define E_ 1024
#define H_ 16
#define D_ 64

typedef __attribute__((ext_vector_type(8))) short short8;
typedef __attribute__((ext_vector_type(4))) float f32x4;

static __device__ __forceinline__ unsigned short f2bf(float x) {
  unsigned int u = __float_as_uint(x);
  unsigned int r = u + 0x7fffu + ((u >> 16) & 1u);  // round-to-nearest-even
  return (unsigned short)(r >> 16);
}
static __device__ __forceinline__ float bf2f(unsigned short b) {
  return __uint_as_float((unsigned int)b << 16);
}

#define GL2LDS16(g, l)                                                            \
  __builtin_amdgcn_global_load_lds(                                               \
      (const __attribute__((address_space(1))) unsigned int*)(g),                 \
      (__attribute__((address_space(3))) unsigned int*)(l), 16, 0, 0)

// ---------- fused preprocessing: mask|mask^T, x->bf16, W->Wt bf16 ----------
__global__ __launch_bounds__(256) void prep_kernel(const int* __restrict__ mask,
                                                   const float* __restrict__ x,
                                                   const float* __restrict__ Wq,
                                                   const float* __restrict__ Wk,
                                                   unsigned char* __restrict__ msym,
                                                   unsigned short* __restrict__ xbf,
                                                   unsigned short* __restrict__ Wt) {
  __shared__ __align__(16) char u_lds[32 * 33 * 4];
  const int blk = blockIdx.x;
  const int tid = threadIdx.x;
  if (blk < 4096) {
    int (*T)[33] = (int(*)[33])u_lds;
    const int b = blk >> 10;
    const int rest = blk & 1023;
    const int i0 = (rest >> 5) << 5;
    const int j0 = (rest & 31) << 5;
    const int ii = tid >> 3;
    const int jj4 = (tid & 7) << 2;
    const size_t bO = (size_t)b * S_ * S_;
    const int4 m2 = *(const int4*)&mask[bO + (size_t)(j0 + ii) * S_ + i0 + jj4];
    T[ii][jj4 + 0] = m2.x; T[ii][jj4 + 1] = m2.y; T[ii][jj4 + 2] = m2.z; T[ii][jj4 + 3] = m2.w;
    __syncthreads();
    const int4 m1 = *(const int4*)&mask[bO + (size_t)(i0 + ii) * S_ + j0 + jj4];
    uchar4 o;
    o.x = ((m1.x != 0) || (T[jj4 + 0][ii] != 0)) ? 1 : 0;
    o.y = ((m1.y != 0) || (T[jj4 + 1][ii] != 0)) ? 1 : 0;
    o.z = ((m1.z != 0) || (T[jj4 + 2][ii] != 0)) ? 1 : 0;
    o.w = ((m1.w != 0) || (T[jj4 + 3][ii] != 0)) ? 1 : 0;
    *(uchar4*)&msym[bO + (size_t)(i0 + ii) * S_ + j0 + jj4] = o;
  } else if (blk < 6144) {
    const size_t i = ((size_t)(blk - 4096) * 256 + tid) * 8;
    const float4 a = *(const float4*)(x + i);
    const float4 b = *(const float4*)(x + i + 4);
    const ushort4 p0 = {f2bf(a.x), f2bf(a.y), f2bf(a.z), f2bf(a.w)};
    const ushort4 p1 = {f2bf(b.x), f2bf(b.y), f2bf(b.z), f2bf(b.w)};
    *(ushort4*)(xbf + i) = p0;
    *(ushort4*)(xbf + i + 4) = p1;
  } else {
    unsigned short (*T2)[36] = (unsigned short(*)[36])u_lds;
    const int wblk = blk - 6144;           // 2 * 32 * 32
    const int mat = wblk >> 10;
    const int kt = (wblk >> 5) & 31, ntb = wblk & 31;
    const float* W = mat ? Wk : Wq;
    const int r = tid >> 3, c4 = (tid & 7) << 2;
    const float4 v = *(const float4*)&W[(size_t)(kt * 32 + r) * 1024 + ntb * 32 + c4];
    T2[r][c4 + 0] = f2bf(v.x); T2[r][c4 + 1] = f2bf(v.y);
    T2[r][c4 + 2] = f2bf(v.z); T2[r][c4 + 3] = f2bf(v.w);
    __syncthreads();
    const ushort4 o = {T2[c4 + 0][r], T2[c4 + 1][r], T2[c4 + 2][r], T2[c4 + 3][r]};
    *(ushort4*)&Wt[(size_t)(mat * 1024 + ntb * 32 + r) * 1024 + kt * 32 + c4] = o;
  }
}

// ------- bf16 MFMA GEMM: P[4096][nstride] = xbf[4096][1024] @ Wt^T (Wt is [n][k]) -----
__global__ __launch_bounds__(256) void gemm_mfma_kernel(const unsigned short* __restrict__ Abf,
                                                        const unsigned short* __restrict__ Wt,
                                                        unsigned short* __restrict__ P,
                                                        int nstride) {
  __shared__ __align__(16) unsigned short As[128 * 32];
  __shared__ __align__(16) unsigned short Bs[128 * 32];
  const int tid = threadIdx.x;
  const int m0 = (blockIdx.x & 31) << 7;
  const int n0 = (blockIdx.x >> 5) << 7;
  const int wave = tid >> 6, lane = tid & 63;
  const int ln15 = lane & 15, rg = lane >> 4;
  const int wm = (wave & 1) << 6;
  const int wn = (wave >> 1) << 6;
  const int sr = tid >> 2;
  const int sc = (tid & 3) << 3;
  const unsigned short* gA = Abf + (size_t)(m0 + sr) * 1024 + sc;
  const unsigned short* gB = Wt + (size_t)(n0 + sr) * 1024 + sc;
  unsigned short* lA = As + tid * 8;
  unsigned short* lB = Bs + tid * 8;
  f32x4 acc[4][4];
#pragma unroll
  for (int i = 0; i < 4; ++i)
#pragma unroll
    for (int j = 0; j < 4; ++j) acc[i][j] = (f32x4){0.0f, 0.0f, 0.0f, 0.0f};

  const unsigned short* pa = As + (wm + ln15) * 32 + rg * 8;
  const unsigned short* pb = Bs + (wn + ln15) * 32 + rg * 8;
  for (int k0 = 0; k0 < E_; k0 += 32) {
    GL2LDS16(gA + k0, lA);
    GL2LDS16(gA + k0 + (size_t)64 * 1024, lA + 2048);
    GL2LDS16(gB + k0, lB);
    GL2LDS16(gB + k0 + (size_t)64 * 1024, lB + 2048);
    __syncthreads();
    short8 af[4], bfr[4];
#pragma unroll
    for (int i = 0; i < 4; ++i) af[i] = *(const short8*)(pa + i * 16 * 32);
#pragma unroll
    for (int j = 0; j < 4; ++j) bfr[j] = *(const short8*)(pb + j * 16 * 32);
#pragma unroll
    for (int i = 0; i < 4; ++i)
#pragma unroll
      for (int j = 0; j < 4; ++j)
        acc[i][j] = __builtin_amdgcn_mfma_f32_16x16x32_bf16(af[i], bfr[j], acc[i][j], 0, 0, 0);
    __syncthreads();
  }
#pragma unroll
  for (int i = 0; i < 4; ++i)
#pragma unroll
    for (int j = 0; j < 4; ++j)
#pragma unroll
      for (int r = 0; r < 4; ++r) {
        const int row = m0 + wm + i * 16 + rg * 4 + r;
        const int col = n0 + wn + j * 16 + ln15;
        P[(size_t)row * nstride + col] = f2bf(acc[i][j][r]);
      }
}

// ---- bias+LN+ReLU from bf16 P (generic, used by split path) ----
__device__ __forceinline__ void ln_body(const unsigned short* p, const float* bias,
                                        const float* gamma, const float* beta,
                                        unsigned short* obf, int b, int s, int tid) {
  const ushort4 pv = *(const ushort4*)(p + tid * 4);
  float4 v = {bf2f(pv.x), bf2f(pv.y), bf2f(pv.z), bf2f(pv.w)};
  const float4 bb = ((const float4*)bias)[tid];
  v.x += bb.x; v.y += bb.y; v.z += bb.z; v.w += bb.w;
  float sum = v.x + v.y + v.z + v.w;
  float s2 = v.x * v.x + v.y * v.y + v.z * v.z + v.w * v.w;
#pragma unroll
  for (int off = 32; off >= 1; off >>= 1) {
    sum += __shfl_xor(sum, off);
    s2 += __shfl_xor(s2, off);
  }
  __shared__ float red[2][4];
  const int wave = tid >> 6, lane = tid & 63;
  if (lane == 0) { red[0][wave] = sum; red[1][wave] = s2; }
  __syncthreads();
  sum = red[0][0] + red[0][1] + red[0][2] + red[0][3];
  s2 = red[1][0] + red[1][1] + red[1][2] + red[1][3];
  const float mu = sum * (1.0f / E_);
  const float var = s2 * (1.0f / E_) - mu * mu;
  const float r = rsqrtf(var + 1e-5f);
  const float4 g = ((const float4*)gamma)[tid];
  const float4 bt = ((const float4*)beta)[tid];
  const float o0 = fmaxf((v.x - mu) * r * g.x + bt.x, 0.0f);
  const float o1 = fmaxf((v.y - mu) * r * g.y + bt.y, 0.0f);
  const float o2 = fmaxf((v.z - mu) * r * g.z + bt.z, 0.0f);
  const float o3 = fmaxf((v.w - mu) * r * g.w + bt.w, 0.0f);
  const int h = tid >> 4;
  const int d = (tid & 15) << 2;
  const ushort4 ob = {f2bf(o0), f2bf(o1), f2bf(o2), f2bf(o3)};
  *(ushort4*)&obf[((size_t)(b * H_ + h) * S_ + s) * D_ + d] = ob;
}

__global__ __launch_bounds__(256) void ln_relu_bf_kernel(const unsigned short* __restrict__ P,
                                                         int rowstride, int coloff,
                                                         const float* __restrict__ bias,
                                                         const float* __restrict__ gamma,
                                                         const float* __restrict__ beta,
                                                         unsigned short* __restrict__ obf) {
  const int row = blockIdx.x;
  ln_body(P + (size_t)row * rowstride + coloff, bias, gamma, beta, obf,
          row >> 10, row & 1023, threadIdx.x);
}

// fused both-LN launch (40MB path): blocks 0..4095 -> Q, 4096..8191 -> K
__global__ __launch_bounds__(256) void ln2_kernel(const unsigned short* __restrict__ P2,
                                                  const float* __restrict__ bq,
                                                  const float* __restrict__ gq,
                                                  const float* __restrict__ bqn,
                                                  const float* __restrict__ bk,
                                                  const float* __restrict__ gk,
                                                  const float* __restrict__ bkn,
                                                  unsigned short* __restrict__ Qbf,
                                                  unsigned short* __restrict__ Kbf) {
  const int blk = blockIdx.x;
  const int sel = blk >> 12;
  const int row = blk & 4095;
  ln_body(P2 + (size_t)row * 2048 + sel * 1024,
          sel ? bk : bq, sel ? gk : gq, sel ? bkn : bqn,
          sel ? Kbf : Qbf, row >> 10, row & 1023, threadIdx.x);
}

// ======= attention v6: head-split blocks (2 blocks/CU), LDS-staged K, atomic head-sum ===
// grid 512: b = blk&3, hh = (blk>>2)&1 (8-head half), qt = blk>>3 (16-q tile).
// XCD = blk&7 -> each XCD works one (b,hh): K-half 1MB + Q-half 1MB L2-resident.
// 512 thr = 8 waves; per step one 128-key tile (16 KB) staged (double-buffered,
// register prefetch depth 1); wave owns keys t*128 + wave*16 + ln15. Per head:
// 8 steps; l via 16-lane shuffle + lane-local LDS sum after the SHARED staging
// barrier (no dedicated l barriers). o[8][4] head-summed in regs; cross-block
// (hh) sum via fp32 atomicAdd into pre-zeroed out.
// MFMA 16x16x32 bf16, C-layout: col(key)=lane&15, row(q)=(lane>>4)*4+reg.
__global__ __launch_bounds__(512, 4) void attn6_kernel(const unsigned short* __restrict__ Qbf,
                                                       const unsigned short* __restrict__ Kbf,
                                                       const unsigned char* __restrict__ msym,
                                                       float* __restrict__ out) {
  __shared__ __align__(16) unsigned short Qs[128 * 64];     // 16 KB: row = hl*16+q
  __shared__ __align__(16) unsigned short Ks[2][128 * 64];  // 32 KB: row = key-in-tile
  __shared__ __align__(16) float l_lds[16][8];              // [q][wave]
  const int tid = threadIdx.x;
  const int wave = tid >> 6, lane = tid & 63;
  const int ln15 = lane & 15, rg = lane >> 4;
  const int b = blockIdx.x & 3;
  const int hh = (blockIdx.x >> 2) & 1;
  const int q0 = (blockIdx.x >> 3) << 4;
  const unsigned short* Kb = Kbf + (size_t)(b * H_ + hh * 8) * S_ * D_;

  // stage Q (8 heads x 16 q x 64 d), XOR-swizzled chunks (p = c ^ (row&7))
  {
    const int rho = tid >> 2;          // 0..127 = hl*16 + q
    const int c0 = (tid & 3) << 1;     // logical chunks c0, c0+1
    const int x = rho & 7;
    const unsigned short* src =
        Qbf + ((size_t)(b * H_ + hh * 8 + (rho >> 4)) * S_ + q0 + (rho & 15)) * D_ + c0 * 8;
    const uint4 v0 = *(const uint4*)src;
    const uint4 v1 = *(const uint4*)(src + 8);
    *(uint4*)&Qs[rho * 64 + (c0 ^ x) * 8] = v0;
    *(uint4*)&Qs[rho * 64 + ((c0 + 1) ^ x) * 8] = v1;
  }
  // K staging thread map
  const int krow = tid >> 2, kc0 = (tid & 3) << 1;
  const int kx = krow & 7;
  const int kp0 = (kc0 ^ kx) * 8, kp1 = ((kc0 + 1) ^ kx) * 8;
  {  // prologue: tile 0
    const unsigned short* src = Kb + (size_t)krow * D_ + kc0 * 8;
    const uint4 p0 = *(const uint4*)src;
    const uint4 p1 = *(const uint4*)(src + 8);
    *(uint4*)&Ks[0][krow * 64 + kp0] = p0;
    *(uint4*)&Ks[0][krow * 64 + kp1] = p1;
  }
  // mask bits: bit(t*4+r) = msym[q0+rg*4+r][t*128 + wave*16 + ln15]
  unsigned int mbits = 0;
#pragma unroll
  for (int t = 0; t < 8; ++t)
#pragma unroll
    for (int r = 0; r < 4; ++r)
      mbits |= (msym[((size_t)b * S_ + q0 + rg * 4 + r) * S_ + t * 128 + wave * 16 + ln15] ? 1u : 0u)
               << (t * 4 + r);
  __syncthreads();

  const int pfrag = (rg ^ (ln15 & 7)) * 8;  // swizzled chunk offset (shorts)
  float o[8][4] = {};

#pragma unroll 1
  for (int hl = 0; hl < 8; ++hl) {
    const unsigned short* qrow = Qs + (hl * 16 + ln15) * 64;
    const short8 a0 = *(const short8*)(qrow + pfrag);
    const short8 a1 = *(const short8*)(qrow + (pfrag ^ 32));
    float la[4] = {0.0f, 0.0f, 0.0f, 0.0f};
    unsigned int epack[8][2];
#pragma unroll
    for (int t = 0; t < 8; ++t) {
      const bool more = (t < 7) || (hl < 7);
      uint4 pf0, pf1;
      if (more) {  // prefetch tile s+1 into registers
        const int s1 = hl * 8 + t + 1;
        const unsigned short* src =
            Kb + ((size_t)(s1 >> 3) * S_ + ((s1 & 7) << 7) + krow) * D_ + kc0 * 8;
        pf0 = *(const uint4*)src;
        pf1 = *(const uint4*)(src + 8);
      }
      // compute tile t from Ks[t&1]
      const unsigned short* kw = Ks[t & 1] + (wave * 16 + ln15) * 64;
      const short8 b0 = *(const short8*)(kw + pfrag);
      const short8 b1 = *(const short8*)(kw + (pfrag ^ 32));
      f32x4 cc = {0.0f, 0.0f, 0.0f, 0.0f};
      cc = __builtin_amdgcn_mfma_f32_16x16x32_bf16(a0, b0, cc, 0, 0, 0);
      cc = __builtin_amdgcn_mfma_f32_16x16x32_bf16(a1, b1, cc, 0, 0, 0);
      float e[4];
#pragma unroll
      for (int r = 0; r < 4; ++r) {
        const float sv = fminf(cc[r] * 0.125f, 80.0f);
        e[r] = ((mbits >> (t * 4 + r)) & 1u) ? 0.0f : __expf(sv);
        la[r] += e[r];
      }
      epack[t][0] = (unsigned)f2bf(e[0]) | ((unsigned)f2bf(e[1]) << 16);
      epack[t][1] = (unsigned)f2bf(e[2]) | ((unsigned)f2bf(e[3]) << 16);
      if (t == 7) {  // head end: 16-lane reduce + publish partials before shared barrier
#pragma unroll
        for (int r = 0; r < 4; ++r) {
          float lv = la[r];
          lv += __shfl_xor(lv, 1);
          lv += __shfl_xor(lv, 2);
          lv += __shfl_xor(lv, 4);
          lv += __shfl_xor(lv, 8);
          la[r] = lv;
        }
        if (ln15 == 0) {
#pragma unroll
          for (int r = 0; r < 4; ++r) l_lds[rg * 4 + r][wave] = la[r];
        }
      }
      if (more) {  // commit prefetched tile to the other buffer
        unsigned short* dst = Ks[(t + 1) & 1];
        *(uint4*)&dst[krow * 64 + kp0] = pf0;
        *(uint4*)&dst[krow * 64 + kp1] = pf1;
      }
      __syncthreads();
    }
    // after the head's last (shared) barrier: lane-local linv + scale into o
#pragma unroll
    for (int r = 0; r < 4; ++r) {
      const float4 va = *(const float4*)&l_lds[rg * 4 + r][0];
      const float4 vb = *(const float4*)&l_lds[rg * 4 + r][4];
      const float ssum = ((va.x + va.y) + (va.z + va.w)) + ((vb.x + vb.y) + (vb.z + vb.w));
      const float li = 0.0625f * __builtin_amdgcn_rcpf(ssum);
#pragma unroll
      for (int t = 0; t < 8; ++t) {
        const unsigned u = epack[t][r >> 1];
        const float ev = (r & 1) ? __uint_as_float(u & 0xFFFF0000u) : __uint_as_float(u << 16);
        o[t][r] += ev * li;
      }
    }
  }
  // cross-block (hh) head-sum via atomics into pre-zeroed out
#pragma unroll
  for (int t = 0; t < 8; ++t)
#pragma unroll
    for (int r = 0; r < 4; ++r)
      atomicAdd(&out[((size_t)b * S_ + q0 + rg * 4 + r) * S_ + t * 128 + wave * 16 + ln15],
                o[t][r]);
}

extern "C" void kernel_launch(void* const* d_in, const int* in_sizes, int n_in,
                              void* d_out, int out_size, void* d_ws, size_t ws_size,
                              hipStream_t stream) {
  const float* x = (const float*)d_in[0];
  const int* mask = (const int*)d_in[1];
  const float* Wq = (const float*)d_in[2];
  const float* bq = (const float*)d_in[3];
  const float* Wk = (const float*)d_in[4];
  const float* bk = (const float*)d_in[5];
  const float* gq = (const float*)d_in[6];
  const float* bq_n = (const float*)d_in[7];
  const float* gk = (const float*)d_in[8];
  const float* bk_n = (const float*)d_in[9];
  float* out = (float*)d_out;

  char* ws = (char*)d_ws;
  const size_t MB = 1024 * 1024;

  if (ws_size >= 40 * MB) {
    // fused layout (40 MB): P2 bf16 [4096][2048] @0 (16), xbf @16 (8, Kbf aliases),
    // Wt @24 (4), Qbf @28 (8), msym @36 (4)
    unsigned short* P2 = (unsigned short*)ws;
    unsigned short* xbf = (unsigned short*)(ws + 16 * MB);
    unsigned short* Kbf = (unsigned short*)(ws + 16 * MB);   // alias: xbf dead after gemm
    unsigned short* Wt = (unsigned short*)(ws + 24 * MB);
    unsigned short* Qbf = (unsigned short*)(ws + 28 * MB);
    unsigned char* msym = (unsigned char*)(ws + 36 * MB);

    prep_kernel<<<8192, 256, 0, stream>>>(mask, x, Wq, Wk, msym, xbf, Wt);
    gemm_mfma_kernel<<<512, 256, 0, stream>>>(xbf, Wt, P2, 2048);
    ln2_kernel<<<8192, 256, 0, stream>>>(P2, bq, gq, bq_n, bk, gk, bk_n, Qbf, Kbf);
    hipMemsetAsync(out, 0, (size_t)B_ * S_ * S_ * sizeof(float), stream);
    attn6_kernel<<<512, 512, 0, stream>>>(Qbf, Kbf, msym, out);
  } else {
    // split layout (32 MB): P bf16 [4096][1024] @0 (8), xbf @8 (8, Kbf aliases),
    // Wt @16 (4), Qbf @20 (8), msym @28 (4)
    unsigned short* P = (unsigned short*)ws;
    unsigned short* xbf = (unsigned short*)(ws + 8 * MB);
    unsigned short* Kbf = (unsigned short*)(ws + 8 * MB);    // alias: xbf dead after 2nd gemm
    unsigned short* Wt = (unsigned short*)(ws + 16 * MB);
    unsigned short* Qbf = (unsigned short*)(ws + 20 * MB);
    unsigned char* msym = (unsigned char*)(ws + 28 * MB);

    prep_kernel<<<8192, 256, 0, stream>>>(mask, x, Wq, Wk, msym, xbf, Wt);
    gemm_mfma_kernel<<<256, 256, 0, stream>>>(xbf, Wt, P, 1024);
    ln_relu_bf_kernel<<<4096, 256, 0, stream>>>(P, 1024, 0, bq, gq, bq_n, Qbf);
    gemm_mfma_kernel<<<256, 256, 0, stream>>>(xbf, Wt + (size_t)1024 * 1024, P, 1024);
    ln_relu_bf_kernel<<<4096, 256, 0, stream>>>(P, 1024, 0, bk, gk, bk_n, Kbf);
    hipMemsetAsync(out, 0, (size_t)B_ * S_ * S_ * sizeof(float), stream);
    attn6_kernel<<<512, 512, 0, stream>>>(Qbf, Kbf, msym, out);
  }
}